// Round 6
// baseline (1116.044 us; speedup 1.0000x reference)
//
#include <hip/hip_runtime.h>

// FiLM LSTM via multi-batch MFMA (R6: raw-barrier pipeline fix):
//   16 blocks x 256 threads (4 waves). Each block owns 16 batches.
//   Per step: Z[16x256] = [H | X_t][16x128] @ [U ; W][128x256] + bias
//   using v_mfma_f32_16x16x32_f16; all 4 gates of a unit land in one lane
//   (gate cols are congruent mod 16) -> lane-local cell update, c in VGPRs.
//   h exchanged via double-buffered XOR-swizzled LDS.
//   KEY: per-step sync is s_waitcnt lgkmcnt(0) + raw s_barrier -- NOT
//   __syncthreads() (which drains vmcnt(0) and would serialize the x
//   prefetch stream with HBM latency every step). x prefetch is 4 deep.

typedef _Float16 f16;
typedef f16  half8 __attribute__((ext_vector_type(8)));
typedef float f32x4 __attribute__((ext_vector_type(4)));

constexpr int Bsz = 256;
constexpr int Tn  = 2048;
constexpr int Dn  = 64;
constexpr int Hn  = 64;
constexpr int G4  = 256;          // 4*H
constexpr int BPB = 16;           // batches per block

__device__ __forceinline__ float sigmoidf_fast(float z) {
    return __builtin_amdgcn_rcpf(1.0f + __expf(-z));
}

// swizzled byte address of h element (batch b, byte offset within 128B row)
__device__ __forceinline__ int haddr(int b, int byte_in_row) {
    return (b * 128 + byte_in_row) ^ ((b & 7) << 4);
}

__global__ __launch_bounds__(256, 1) void lstm_film_mfma(
    const float* __restrict__ x,     // [B,T,64]
    const float* __restrict__ W,     // [64,256]
    const float* __restrict__ U,     // [64,256]
    const float* __restrict__ bias,  // [256]
    const float* __restrict__ wg, const float* __restrict__ bgam,
    const float* __restrict__ wb, const float* __restrict__ bbet,
    float* __restrict__ out)         // gamma[256] then beta[256]
{
    __shared__ __align__(16) f16 hbuf[2][BPB * Hn];   // 2 x 2KB, swizzled

    const int tid  = threadIdx.x;
    const int w    = tid >> 6;        // wave 0..3
    const int l    = tid & 63;        // lane
    const int lrow = l & 15;          // A-row / C-col index
    const int kgrp = l >> 4;          // 0..3

    // ---- B fragments: Bf[kf][q], kf: 0,1 = U rows 0-31/32-63; 2,3 = W ----
    half8 Bf[4][4];
#pragma unroll
    for (int kf = 0; kf < 4; ++kf) {
        const float* M = (kf < 2) ? U : W;
        const int krow0 = (kf & 1) * 32 + kgrp * 8;
#pragma unroll
        for (int q = 0; q < 4; ++q) {
            const int col = q * 64 + w * 16 + lrow;
#pragma unroll
            for (int j = 0; j < 8; ++j)
                Bf[kf][q][j] = (f16)M[(krow0 + j) * G4 + col];
        }
    }
    float bq[4];
#pragma unroll
    for (int q = 0; q < 4; ++q) bq[q] = bias[q * 64 + w * 16 + lrow];

    // ---- init h buffers to zero and c ----
    ((uint4*)hbuf)[tid] = uint4{0, 0, 0, 0};   // 256 x 16B = both buffers
    float c0 = 0.f, c1 = 0.f, c2 = 0.f, c3 = 0.f;

    // ---- x addressing: lane covers batch=lrow, x cols kgrp*8..+7 (+32) ----
    const float* xlane = x + ((size_t)(blockIdx.x * BPB + lrow) * Tn) * Dn + kgrp * 8;

    // h-frag LDS byte addresses (swizzled; XOR keeps 16B blocks intact)
    const int rdA = haddr(lrow, kgrp * 16);        // k 0..31 slice
    const int rdB = haddr(lrow, kgrp * 16 + 64);   // k 32..63 slice
    const int wr0 = haddr(kgrp * 4 + 0, (w * 16 + lrow) * 2);
    const int wr1 = haddr(kgrp * 4 + 1, (w * 16 + lrow) * 2);
    const int wr2 = haddr(kgrp * 4 + 2, (w * 16 + lrow) * 2);
    const int wr3 = haddr(kgrp * 4 + 3, (w * 16 + lrow) * 2);

    __syncthreads();   // hbuf cleared (full barrier once is fine)

#define XLOAD(dst, T) do {                                                   \
        const float* p_ = xlane + (size_t)(T) * Dn;                          \
        dst[0] = *(const float4*)(p_);                                       \
        dst[1] = *(const float4*)(p_ + 4);                                   \
        dst[2] = *(const float4*)(p_ + 32);                                  \
        dst[3] = *(const float4*)(p_ + 36);                                  \
    } while (0)

    float4 LD0[4], LD1[4], LD2[4], LD3[4];
    XLOAD(LD0, 0);
    XLOAD(LD1, 1);
    XLOAD(LD2, 2);
    XLOAD(LD3, 3);

#define STEP(LD, PBUF, TNEXT) do {                                           \
        const f16* hb = hbuf[PBUF];                                          \
        half8 ah0 = *(const half8*)((const char*)hb + rdA);                  \
        half8 ah1 = *(const half8*)((const char*)hb + rdB);                  \
        half8 ax0, ax1;                                                      \
        ax0[0]=(f16)LD[0].x; ax0[1]=(f16)LD[0].y; ax0[2]=(f16)LD[0].z;       \
        ax0[3]=(f16)LD[0].w; ax0[4]=(f16)LD[1].x; ax0[5]=(f16)LD[1].y;       \
        ax0[6]=(f16)LD[1].z; ax0[7]=(f16)LD[1].w;                            \
        ax1[0]=(f16)LD[2].x; ax1[1]=(f16)LD[2].y; ax1[2]=(f16)LD[2].z;       \
        ax1[3]=(f16)LD[2].w; ax1[4]=(f16)LD[3].x; ax1[5]=(f16)LD[3].y;       \
        ax1[6]=(f16)LD[3].z; ax1[7]=(f16)LD[3].w;                            \
        XLOAD(LD, TNEXT);                                                    \
        /* x-side chains (independent of h ds_read) */                       \
        f32x4 x0 = {0.f,0.f,0.f,0.f}, x1 = x0, x2 = x0, x3 = x0;             \
        x0 = __builtin_amdgcn_mfma_f32_16x16x32_f16(ax0, Bf[2][0], x0,0,0,0);\
        x1 = __builtin_amdgcn_mfma_f32_16x16x32_f16(ax0, Bf[2][1], x1,0,0,0);\
        x2 = __builtin_amdgcn_mfma_f32_16x16x32_f16(ax0, Bf[2][2], x2,0,0,0);\
        x3 = __builtin_amdgcn_mfma_f32_16x16x32_f16(ax0, Bf[2][3], x3,0,0,0);\
        x0 = __builtin_amdgcn_mfma_f32_16x16x32_f16(ax1, Bf[3][0], x0,0,0,0);\
        x1 = __builtin_amdgcn_mfma_f32_16x16x32_f16(ax1, Bf[3][1], x1,0,0,0);\
        x2 = __builtin_amdgcn_mfma_f32_16x16x32_f16(ax1, Bf[3][2], x2,0,0,0);\
        x3 = __builtin_amdgcn_mfma_f32_16x16x32_f16(ax1, Bf[3][3], x3,0,0,0);\
        /* h-side chains */                                                  \
        f32x4 z0 = {bq[0], bq[0], bq[0], bq[0]};                             \
        f32x4 z1 = {bq[1], bq[1], bq[1], bq[1]};                             \
        f32x4 z2 = {bq[2], bq[2], bq[2], bq[2]};                             \
        f32x4 z3 = {bq[3], bq[3], bq[3], bq[3]};                             \
        z0 = __builtin_amdgcn_mfma_f32_16x16x32_f16(ah0, Bf[0][0], z0,0,0,0);\
        z1 = __builtin_amdgcn_mfma_f32_16x16x32_f16(ah0, Bf[0][1], z1,0,0,0);\
        z2 = __builtin_amdgcn_mfma_f32_16x16x32_f16(ah0, Bf[0][2], z2,0,0,0);\
        z3 = __builtin_amdgcn_mfma_f32_16x16x32_f16(ah0, Bf[0][3], z3,0,0,0);\
        z0 = __builtin_amdgcn_mfma_f32_16x16x32_f16(ah1, Bf[1][0], z0,0,0,0);\
        z1 = __builtin_amdgcn_mfma_f32_16x16x32_f16(ah1, Bf[1][1], z1,0,0,0);\
        z2 = __builtin_amdgcn_mfma_f32_16x16x32_f16(ah1, Bf[1][2], z2,0,0,0);\
        z3 = __builtin_amdgcn_mfma_f32_16x16x32_f16(ah1, Bf[1][3], z3,0,0,0);\
        z0 += x0; z1 += x1; z2 += x2; z3 += x3;                              \
        f16* ho = hbuf[(PBUF) ^ 1];                                          \
        {                                                                    \
            float gi, gf, gg, go, hh;                                        \
            gi = sigmoidf_fast(z0[0]); gf = sigmoidf_fast(z1[0]);            \
            gg = sigmoidf_fast(z2[0]); go = sigmoidf_fast(z3[0]);            \
            c0 = fmaf(gf, c0, gi * gg); hh = go * sigmoidf_fast(c0);         \
            *(f16*)((char*)ho + wr0) = (f16)hh;                              \
            gi = sigmoidf_fast(z0[1]); gf = sigmoidf_fast(z1[1]);            \
            gg = sigmoidf_fast(z2[1]); go = sigmoidf_fast(z3[1]);            \
            c1 = fmaf(gf, c1, gi * gg); hh = go * sigmoidf_fast(c1);         \
            *(f16*)((char*)ho + wr1) = (f16)hh;                              \
            gi = sigmoidf_fast(z0[2]); gf = sigmoidf_fast(z1[2]);            \
            gg = sigmoidf_fast(z2[2]); go = sigmoidf_fast(z3[2]);            \
            c2 = fmaf(gf, c2, gi * gg); hh = go * sigmoidf_fast(c2);         \
            *(f16*)((char*)ho + wr2) = (f16)hh;                              \
            gi = sigmoidf_fast(z0[3]); gf = sigmoidf_fast(z1[3]);            \
            gg = sigmoidf_fast(z2[3]); go = sigmoidf_fast(z3[3]);            \
            c3 = fmaf(gf, c3, gi * gg); hh = go * sigmoidf_fast(c3);         \
            *(f16*)((char*)ho + wr3) = (f16)hh;                              \
        }                                                                    \
        /* drain LDS writes only; global x prefetch stays in flight */       \
        asm volatile("s_waitcnt lgkmcnt(0)" ::: "memory");                   \
        __builtin_amdgcn_s_barrier();                                        \
        asm volatile("" ::: "memory");                                       \
    } while (0)

    for (int t = 0; t < Tn; t += 4) {
        const int tA = t + 4 < Tn ? t + 4 : Tn - 1;
        const int tB = t + 5 < Tn ? t + 5 : Tn - 1;
        const int tC = t + 6 < Tn ? t + 6 : Tn - 1;
        const int tD = t + 7 < Tn ? t + 7 : Tn - 1;
        STEP(LD0, 0, tA);   // even step reads hbuf[0], writes hbuf[1]
        STEP(LD1, 1, tB);
        STEP(LD2, 0, tC);
        STEP(LD3, 1, tD);
    }
#undef STEP
#undef XLOAD

    // ---- heads: final h in hbuf[0]; wave w reduces batches 4w..4w+3 ----
    const float wgj = wg[l], wbj = wb[l];
#pragma unroll
    for (int r = 0; r < 4; ++r) {
        const int b = w * 4 + r;
        float hv = (float)*(const f16*)((const char*)hbuf[0] + haddr(b, l * 2));
        float vg = hv * wgj, vb = hv * wbj;
#pragma unroll
        for (int off = 32; off > 0; off >>= 1) {
            vg += __shfl_xor(vg, off, 64);
            vb += __shfl_xor(vb, off, 64);
        }
        if (l == 0) {
            out[blockIdx.x * BPB + b]       = vg + bgam[0];
            out[Bsz + blockIdx.x * BPB + b] = vb + bbet[0];
        }
    }
}

extern "C" void kernel_launch(void* const* d_in, const int* in_sizes, int n_in,
                              void* d_out, int out_size, void* d_ws, size_t ws_size,
                              hipStream_t stream) {
    const float* x    = (const float*)d_in[0];
    const float* W    = (const float*)d_in[2];
    const float* U    = (const float*)d_in[3];
    const float* bias = (const float*)d_in[4];
    const float* wg   = (const float*)d_in[5];
    const float* bgam = (const float*)d_in[6];
    const float* wb   = (const float*)d_in[7];
    const float* bbet = (const float*)d_in[8];
    float* out = (float*)d_out;

    lstm_film_mfma<<<Bsz / BPB, 256, 0, stream>>>(x, W, U, bias,
                                                  wg, bgam, wb, bbet, out);
}

// Round 7
// 956.950 us; speedup vs baseline: 1.1663x; 1.1663x over previous
//
#include <hip/hip_runtime.h>

// FiLM LSTM, R7: MFMA recurrence + f16 x-prepass.
//   Kernel 1 (prepass): x f32 [B,T,64] -> f16 x16 [B,T,64] in d_ws (64 MB).
//   Kernel 2: 16 blocks x 256 threads (4 waves), 16 batches/block.
//     Per step: Z[16x256] = [H|X_t][16x128] @ [U;W][128x256] + bias via
//     v_mfma_f32_16x16x32_f16. Gate cols of one unit are congruent mod 16 ->
//     all 4 gates land in one lane; cell update lane-local, c in VGPRs.
//     h via double-buffered XOR-swizzled LDS; per-step sync = lgkmcnt(0) +
//     raw s_barrier (x loads stay in flight). x A-frags = 2 dwordx4/step,
//     4-step register rotation, zero cvt in the loop.

typedef _Float16 f16;
typedef f16  half8 __attribute__((ext_vector_type(8)));
typedef float f32x4 __attribute__((ext_vector_type(4)));

constexpr int Bsz = 256;
constexpr int Tn  = 2048;
constexpr int Dn  = 64;
constexpr int Hn  = 64;
constexpr int G4  = 256;          // 4*H
constexpr int BPB = 16;           // batches per block

__device__ __forceinline__ float sigmoidf_fast(float z) {
    return __builtin_amdgcn_rcpf(1.0f + __expf(-z));
}

// swizzled byte address of h element (batch b, byte offset within 128B row)
__device__ __forceinline__ int haddr(int b, int byte_in_row) {
    return (b * 128 + byte_in_row) ^ ((b & 7) << 4);
}

// ---------------- prepass: f32 -> f16 convert ----------------
__global__ __launch_bounds__(256) void xcvt_kernel(
    const float* __restrict__ x, f16* __restrict__ x16, int n8)
{
    int i = blockIdx.x * blockDim.x + threadIdx.x;
    const int stride = gridDim.x * blockDim.x;
    for (; i < n8; i += stride) {
        float4 a = ((const float4*)x)[2 * i];
        float4 b = ((const float4*)x)[2 * i + 1];
        half8 o;
        o[0] = (f16)a.x; o[1] = (f16)a.y; o[2] = (f16)a.z; o[3] = (f16)a.w;
        o[4] = (f16)b.x; o[5] = (f16)b.y; o[6] = (f16)b.z; o[7] = (f16)b.w;
        ((half8*)x16)[i] = o;
    }
}

// ---------------- serial MFMA recurrence ----------------
__global__ __launch_bounds__(256, 1) void lstm_film_mfma(
    const f16* __restrict__ x16,     // [B,T,64] f16
    const float* __restrict__ W,     // [64,256]
    const float* __restrict__ U,     // [64,256]
    const float* __restrict__ bias,  // [256]
    const float* __restrict__ wg, const float* __restrict__ bgam,
    const float* __restrict__ wb, const float* __restrict__ bbet,
    float* __restrict__ out)         // gamma[256] then beta[256]
{
    __shared__ __align__(16) f16 hbuf[2][BPB * Hn];   // 2 x 2KB, swizzled

    const int tid  = threadIdx.x;
    const int w    = tid >> 6;        // wave 0..3
    const int l    = tid & 63;        // lane
    const int lrow = l & 15;          // A-row / C-col index
    const int kgrp = l >> 4;          // 0..3

    // ---- B fragments: Bf[kf][q]; kf 0,1 = U k 0-31/32-63; kf 2,3 = W ----
    half8 Bf[4][4];
#pragma unroll
    for (int kf = 0; kf < 4; ++kf) {
        const float* M = (kf < 2) ? U : W;
        const int krow0 = (kf & 1) * 32 + kgrp * 8;
#pragma unroll
        for (int q = 0; q < 4; ++q) {
            const int col = q * 64 + w * 16 + lrow;
#pragma unroll
            for (int j = 0; j < 8; ++j)
                Bf[kf][q][j] = (f16)M[(krow0 + j) * G4 + col];
        }
    }
    float bq[4];
#pragma unroll
    for (int q = 0; q < 4; ++q) bq[q] = bias[q * 64 + w * 16 + lrow];

    // ---- init h buffers to zero and c ----
    ((uint4*)hbuf)[tid] = uint4{0, 0, 0, 0};   // 256 x 16B = both buffers
    float c0 = 0.f, c1 = 0.f, c2 = 0.f, c3 = 0.f;

    // ---- x addressing: lane covers batch=lrow; ax0 at col kgrp*8, ax1 +32
    const f16* xlane = x16 + ((size_t)(blockIdx.x * BPB + lrow) * Tn) * Dn
                           + kgrp * 8;

    const int rdA = haddr(lrow, kgrp * 16);        // h k 0..31 slice
    const int rdB = haddr(lrow, kgrp * 16 + 64);   // h k 32..63 slice
    const int wr0 = haddr(kgrp * 4 + 0, (w * 16 + lrow) * 2);
    const int wr1 = haddr(kgrp * 4 + 1, (w * 16 + lrow) * 2);
    const int wr2 = haddr(kgrp * 4 + 2, (w * 16 + lrow) * 2);
    const int wr3 = haddr(kgrp * 4 + 3, (w * 16 + lrow) * 2);

    __syncthreads();   // hbuf cleared

#define XLD0(T) (*(const half8*)(xlane + (size_t)(T) * Dn))
#define XLD1(T) (*(const half8*)(xlane + (size_t)(T) * Dn + 32))

    half8 A0 = XLD0(0), B0 = XLD1(0);
    half8 A1 = XLD0(1), B1 = XLD1(1);
    half8 A2 = XLD0(2), B2 = XLD1(2);
    half8 A3 = XLD0(3), B3 = XLD1(3);

#define STEP(AX0, AX1, PBUF, TNEXT) do {                                     \
        const f16* hb = hbuf[PBUF];                                          \
        half8 ah0 = *(const half8*)((const char*)hb + rdA);                  \
        half8 ah1 = *(const half8*)((const char*)hb + rdB);                  \
        /* x-side first: independent of the ds_read above */                 \
        f32x4 z0 = {bq[0], bq[0], bq[0], bq[0]};                             \
        f32x4 z1 = {bq[1], bq[1], bq[1], bq[1]};                             \
        f32x4 z2 = {bq[2], bq[2], bq[2], bq[2]};                             \
        f32x4 z3 = {bq[3], bq[3], bq[3], bq[3]};                             \
        z0 = __builtin_amdgcn_mfma_f32_16x16x32_f16(AX0, Bf[2][0], z0,0,0,0);\
        z1 = __builtin_amdgcn_mfma_f32_16x16x32_f16(AX0, Bf[2][1], z1,0,0,0);\
        z2 = __builtin_amdgcn_mfma_f32_16x16x32_f16(AX0, Bf[2][2], z2,0,0,0);\
        z3 = __builtin_amdgcn_mfma_f32_16x16x32_f16(AX0, Bf[2][3], z3,0,0,0);\
        z0 = __builtin_amdgcn_mfma_f32_16x16x32_f16(AX1, Bf[3][0], z0,0,0,0);\
        z1 = __builtin_amdgcn_mfma_f32_16x16x32_f16(AX1, Bf[3][1], z1,0,0,0);\
        z2 = __builtin_amdgcn_mfma_f32_16x16x32_f16(AX1, Bf[3][2], z2,0,0,0);\
        z3 = __builtin_amdgcn_mfma_f32_16x16x32_f16(AX1, Bf[3][3], z3,0,0,0);\
        /* reload this rotation slot for t+4 (issue after last AX use) */    \
        AX0 = XLD0(TNEXT); AX1 = XLD1(TNEXT);                                \
        /* h-side */                                                         \
        z0 = __builtin_amdgcn_mfma_f32_16x16x32_f16(ah0, Bf[0][0], z0,0,0,0);\
        z1 = __builtin_amdgcn_mfma_f32_16x16x32_f16(ah0, Bf[0][1], z1,0,0,0);\
        z2 = __builtin_amdgcn_mfma_f32_16x16x32_f16(ah0, Bf[0][2], z2,0,0,0);\
        z3 = __builtin_amdgcn_mfma_f32_16x16x32_f16(ah0, Bf[0][3], z3,0,0,0);\
        z0 = __builtin_amdgcn_mfma_f32_16x16x32_f16(ah1, Bf[1][0], z0,0,0,0);\
        z1 = __builtin_amdgcn_mfma_f32_16x16x32_f16(ah1, Bf[1][1], z1,0,0,0);\
        z2 = __builtin_amdgcn_mfma_f32_16x16x32_f16(ah1, Bf[1][2], z2,0,0,0);\
        z3 = __builtin_amdgcn_mfma_f32_16x16x32_f16(ah1, Bf[1][3], z3,0,0,0);\
        f16* ho = hbuf[(PBUF) ^ 1];                                          \
        {                                                                    \
            float gi, gf, gg, go, hh;                                        \
            gi = sigmoidf_fast(z0[0]); gf = sigmoidf_fast(z1[0]);            \
            gg = sigmoidf_fast(z2[0]); go = sigmoidf_fast(z3[0]);            \
            c0 = fmaf(gf, c0, gi * gg); hh = go * sigmoidf_fast(c0);         \
            *(f16*)((char*)ho + wr0) = (f16)hh;                              \
            gi = sigmoidf_fast(z0[1]); gf = sigmoidf_fast(z1[1]);            \
            gg = sigmoidf_fast(z2[1]); go = sigmoidf_fast(z3[1]);            \
            c1 = fmaf(gf, c1, gi * gg); hh = go * sigmoidf_fast(c1);         \
            *(f16*)((char*)ho + wr1) = (f16)hh;                              \
            gi = sigmoidf_fast(z0[2]); gf = sigmoidf_fast(z1[2]);            \
            gg = sigmoidf_fast(z2[2]); go = sigmoidf_fast(z3[2]);            \
            c2 = fmaf(gf, c2, gi * gg); hh = go * sigmoidf_fast(c2);         \
            *(f16*)((char*)ho + wr2) = (f16)hh;                              \
            gi = sigmoidf_fast(z0[3]); gf = sigmoidf_fast(z1[3]);            \
            gg = sigmoidf_fast(z2[3]); go = sigmoidf_fast(z3[3]);            \
            c3 = fmaf(gf, c3, gi * gg); hh = go * sigmoidf_fast(c3);         \
            *(f16*)((char*)ho + wr3) = (f16)hh;                              \
        }                                                                    \
        asm volatile("s_waitcnt lgkmcnt(0)" ::: "memory");                   \
        __builtin_amdgcn_s_barrier();                                        \
        asm volatile("" ::: "memory");                                       \
    } while (0)

    for (int t = 0; t < Tn; t += 4) {
        const int tA = t + 4 < Tn ? t + 4 : Tn - 1;
        const int tB = t + 5 < Tn ? t + 5 : Tn - 1;
        const int tC = t + 6 < Tn ? t + 6 : Tn - 1;
        const int tD = t + 7 < Tn ? t + 7 : Tn - 1;
        STEP(A0, B0, 0, tA);   // even step reads hbuf[0], writes hbuf[1]
        STEP(A1, B1, 1, tB);
        STEP(A2, B2, 0, tC);
        STEP(A3, B3, 1, tD);
    }
#undef STEP
#undef XLD0
#undef XLD1

    // ---- heads: final h in hbuf[0]; wave w reduces batches 4w..4w+3 ----
    const float wgj = wg[l], wbj = wb[l];
#pragma unroll
    for (int r = 0; r < 4; ++r) {
        const int b = w * 4 + r;
        float hv = (float)*(const f16*)((const char*)hbuf[0] + haddr(b, l * 2));
        float vg = hv * wgj, vb = hv * wbj;
#pragma unroll
        for (int off = 32; off > 0; off >>= 1) {
            vg += __shfl_xor(vg, off, 64);
            vb += __shfl_xor(vb, off, 64);
        }
        if (l == 0) {
            out[blockIdx.x * BPB + b]       = vg + bgam[0];
            out[Bsz + blockIdx.x * BPB + b] = vb + bbet[0];
        }
    }
}

// ---------------- fallback (R4 fused, no workspace) ----------------
typedef f16 f16x2 __attribute__((ext_vector_type(2)));
typedef f16 f16x4 __attribute__((ext_vector_type(4)));

__device__ __forceinline__ float dot2acc(f16x2 a, f16x2 b, float acc) {
    return acc + (float)a[0] * (float)b[0] + (float)a[1] * (float)b[1];
}
__device__ __forceinline__ f16x2 asf16x2(unsigned int u) {
    union { unsigned int u; f16x2 h; } v; v.u = u; return v.h;
}

constexpr int CHS = 32;
constexpr int NC  = Tn / CHS;
constexpr int XSTR = 72;

__global__ __launch_bounds__(128, 1) void lstm_film_fused(
    const float* __restrict__ x, const float* __restrict__ W,
    const float* __restrict__ U, const float* __restrict__ bias,
    const float* __restrict__ wg, const float* __restrict__ bgam,
    const float* __restrict__ wb, const float* __restrict__ bbet,
    float* __restrict__ out)
{
    __shared__ f16x4 zbuf[2][CHS][Hn];
    __shared__ __align__(16) f16 hl[Hn];
    __shared__ __align__(16) f16 xstage[CHS * XSTR];
    const int wave = threadIdx.x >> 6, j = threadIdx.x & 63, b = blockIdx.x;
    const float* xb = x + (size_t)b * Tn * Dn;
    if (wave == 1) {
        f16x2 Wp[4][32]; float bg[4];
#pragma unroll
        for (int q = 0; q < 4; ++q) {
#pragma unroll
            for (int k2 = 0; k2 < 32; ++k2) {
                Wp[q][k2][0] = (f16)W[(2 * k2 + 0) * G4 + q * 64 + j];
                Wp[q][k2][1] = (f16)W[(2 * k2 + 1) * G4 + q * 64 + j];
            }
            bg[q] = bias[q * 64 + j];
        }
        const int row0 = j >> 4, part = j & 15;
        float4 xld[8];
#pragma unroll
        for (int p = 0; p < 8; ++p)
            xld[p] = ((const float4*)(xb + (size_t)(p * 4 + row0) * Dn))[part];
        for (int ch = 0; ch < NC; ++ch) {
#pragma unroll
            for (int p = 0; p < 8; ++p) {
                float4 v = xld[p];
                f16x4 o; o[0]=(f16)v.x; o[1]=(f16)v.y; o[2]=(f16)v.z; o[3]=(f16)v.w;
                *(f16x4*)(xstage + (p * 4 + row0) * XSTR + part * 4) = o;
            }
            if (ch + 1 < NC) {
#pragma unroll
                for (int p = 0; p < 8; ++p)
                    xld[p] = ((const float4*)(xb +
                        (size_t)((ch + 1) * CHS + p * 4 + row0) * Dn))[part];
            }
#pragma unroll 1
            for (int s = 0; s < CHS; ++s) {
                const uint4* xr = (const uint4*)(xstage + s * XSTR);
                float a0 = bg[0], a1 = bg[1], a2 = bg[2], a3 = bg[3];
#pragma unroll
                for (int kk = 0; kk < 8; ++kk) {
                    uint4 w4 = xr[kk];
                    f16x2 p0 = asf16x2(w4.x), p1 = asf16x2(w4.y);
                    f16x2 p2 = asf16x2(w4.z), p3 = asf16x2(w4.w);
                    a0=dot2acc(p0,Wp[0][kk*4+0],a0); a1=dot2acc(p0,Wp[1][kk*4+0],a1);
                    a2=dot2acc(p0,Wp[2][kk*4+0],a2); a3=dot2acc(p0,Wp[3][kk*4+0],a3);
                    a0=dot2acc(p1,Wp[0][kk*4+1],a0); a1=dot2acc(p1,Wp[1][kk*4+1],a1);
                    a2=dot2acc(p1,Wp[2][kk*4+1],a2); a3=dot2acc(p1,Wp[3][kk*4+1],a3);
                    a0=dot2acc(p2,Wp[0][kk*4+2],a0); a1=dot2acc(p2,Wp[1][kk*4+2],a1);
                    a2=dot2acc(p2,Wp[2][kk*4+2],a2); a3=dot2acc(p2,Wp[3][kk*4+2],a3);
                    a0=dot2acc(p3,Wp[0][kk*4+3],a0); a1=dot2acc(p3,Wp[1][kk*4+3],a1);
                    a2=dot2acc(p3,Wp[2][kk*4+3],a2); a3=dot2acc(p3,Wp[3][kk*4+3],a3);
                }
                f16x4 zo; zo[0]=(f16)a0; zo[1]=(f16)a1; zo[2]=(f16)a2; zo[3]=(f16)a3;
                zbuf[ch & 1][s][j] = zo;
            }
            __syncthreads();
        }
    } else {
        f16x2 Up[4][32];
#pragma unroll
        for (int q = 0; q < 4; ++q)
#pragma unroll
            for (int k2 = 0; k2 < 32; ++k2) {
                Up[q][k2][0] = (f16)U[(2 * k2 + 0) * G4 + q * 64 + j];
                Up[q][k2][1] = (f16)U[(2 * k2 + 1) * G4 + q * 64 + j];
            }
        const float wgj = wg[j], wbj = wb[j];
        const float bg0 = bgam[0], bb0 = bbet[0];
        float h = 0.0f, cc = 0.0f;
        hl[j] = (f16)0.0f;
        auto consume = [&](int chk) {
            const int bb2 = chk & 1;
            f16x4 zc = zbuf[bb2][0][j];
#pragma unroll 1
            for (int s = 0; s < CHS; ++s) {
                f16x4 zn = zbuf[bb2][(s + 1 < CHS) ? s + 1 : CHS - 1][j];
                float a0 = (float)zc[0], a1 = (float)zc[1];
                float a2 = (float)zc[2], a3 = (float)zc[3];
                const uint4* hv = (const uint4*)hl;
#pragma unroll
                for (int kk = 0; kk < 8; ++kk) {
                    uint4 w4 = hv[kk];
                    f16x2 p0 = asf16x2(w4.x), p1 = asf16x2(w4.y);
                    f16x2 p2 = asf16x2(w4.z), p3 = asf16x2(w4.w);
                    a0=dot2acc(p0,Up[0][kk*4+0],a0); a1=dot2acc(p0,Up[1][kk*4+0],a1);
                    a2=dot2acc(p0,Up[2][kk*4+0],a2); a3=dot2acc(p0,Up[3][kk*4+0],a3);
                    a0=dot2acc(p1,Up[0][kk*4+1],a0); a1=dot2acc(p1,Up[1][kk*4+1],a1);
                    a2=dot2acc(p1,Up[2][kk*4+1],a2); a3=dot2acc(p1,Up[3][kk*4+1],a3);
                    a0=dot2acc(p2,Up[0][kk*4+2],a0); a1=dot2acc(p2,Up[1][kk*4+2],a1);
                    a2=dot2acc(p2,Up[2][kk*4+2],a2); a3=dot2acc(p2,Up[3][kk*4+2],a3);
                    a0=dot2acc(p3,Up[0][kk*4+3],a0); a1=dot2acc(p3,Up[1][kk*4+3],a1);
                    a2=dot2acc(p3,Up[2][kk*4+3],a2); a3=dot2acc(p3,Up[3][kk*4+3],a3);
                }
                float gi = sigmoidf_fast(a0), gf = sigmoidf_fast(a1);
                float gg = sigmoidf_fast(a2), go = sigmoidf_fast(a3);
                cc = fmaf(gf, cc, gi * gg);
                h = go * sigmoidf_fast(cc);
                hl[j] = (f16)h;
                zc = zn;
            }
        };
        __syncthreads();
        for (int ch = 1; ch < NC; ++ch) { consume(ch - 1); __syncthreads(); }
        consume(NC - 1);
        float vg = h * wgj, vb = h * wbj;
#pragma unroll
        for (int off = 32; off > 0; off >>= 1) {
            vg += __shfl_xor(vg, off, 64);
            vb += __shfl_xor(vb, off, 64);
        }
        if (j == 0) { out[b] = vg + bg0; out[Bsz + b] = vb + bb0; }
    }
}

extern "C" void kernel_launch(void* const* d_in, const int* in_sizes, int n_in,
                              void* d_out, int out_size, void* d_ws, size_t ws_size,
                              hipStream_t stream) {
    const float* x    = (const float*)d_in[0];
    const float* W    = (const float*)d_in[2];
    const float* U    = (const float*)d_in[3];
    const float* bias = (const float*)d_in[4];
    const float* wg   = (const float*)d_in[5];
    const float* bgam = (const float*)d_in[6];
    const float* wb   = (const float*)d_in[7];
    const float* bbet = (const float*)d_in[8];
    float* out = (float*)d_out;

    const size_t x16_bytes = (size_t)Bsz * Tn * Dn * sizeof(f16);  // 64 MB
    if (ws_size >= x16_bytes) {
        f16* x16 = (f16*)d_ws;
        const int n8 = Bsz * Tn * Dn / 8;
        xcvt_kernel<<<2048, 256, 0, stream>>>(x, x16, n8);
        lstm_film_mfma<<<Bsz / BPB, 256, 0, stream>>>(x16, W, U, bias,
                                                      wg, bgam, wb, bbet, out);
    } else {
        lstm_film_fused<<<Bsz, 128, 0, stream>>>(x, W, U, bias,
                                                 wg, bgam, wb, bbet, out);
    }
}

// Round 8
// 523.045 us; speedup vs baseline: 2.1337x; 1.8296x over previous
//
#include <hip/hip_runtime.h>

// FiLM LSTM, R8: MFMA recurrence, 4 batches/block over 64 CUs.
//   Kernel 1 (prepass): x f32 -> f16 in d_ws (64 MB).
//   Kernel 2: 64 blocks x 256 threads (4 waves), BPB=4 batches/block.
//     Per step: Z[16x256] = [H|X_t][16x128] @ [U;W][128x256] + bias via
//     v_mfma_f32_16x16x32_f16, batches mapped to C-rows {0,4,8,12} = reg 0
//     of every lane -> each lane owns exactly ONE (batch,unit) pair:
//     cell update is 1 pair/lane (10 trans-ops/step vs 40 at BPB=16).
//     MFMA rows 1..3 of each group are padding (garbage-in, discarded-out).
//     h via tiny double-buffered LDS [2][4][80] f16; one raw
//     lgkmcnt(0)+s_barrier per step; x loads stay in flight across it.

typedef _Float16 f16;
typedef f16  half8 __attribute__((ext_vector_type(8)));
typedef float f32x4 __attribute__((ext_vector_type(4)));

constexpr int Bsz = 256;
constexpr int Tn  = 2048;
constexpr int Dn  = 64;
constexpr int Hn  = 64;
constexpr int G4  = 256;          // 4*H
constexpr int BPB = 4;            // batches per block
constexpr int HSTR = 160;         // bytes per batch row in h LDS (80 f16)

__device__ __forceinline__ float sigmoidf_fast(float z) {
    return __builtin_amdgcn_rcpf(1.0f + __expf(-z));
}

// ---------------- prepass: f32 -> f16 convert ----------------
__global__ __launch_bounds__(256) void xcvt_kernel(
    const float* __restrict__ x, f16* __restrict__ x16, int n8)
{
    int i = blockIdx.x * blockDim.x + threadIdx.x;
    const int stride = gridDim.x * blockDim.x;
    for (; i < n8; i += stride) {
        float4 a = ((const float4*)x)[2 * i];
        float4 b = ((const float4*)x)[2 * i + 1];
        half8 o;
        o[0] = (f16)a.x; o[1] = (f16)a.y; o[2] = (f16)a.z; o[3] = (f16)a.w;
        o[4] = (f16)b.x; o[5] = (f16)b.y; o[6] = (f16)b.z; o[7] = (f16)b.w;
        ((half8*)x16)[i] = o;
    }
}

// ---------------- serial MFMA recurrence ----------------
__global__ __launch_bounds__(256, 1) void lstm_film_mfma(
    const f16* __restrict__ x16,     // [B,T,64] f16
    const float* __restrict__ W,     // [64,256]
    const float* __restrict__ U,     // [64,256]
    const float* __restrict__ bias,  // [256]
    const float* __restrict__ wg, const float* __restrict__ bgam,
    const float* __restrict__ wb, const float* __restrict__ bbet,
    float* __restrict__ out)         // gamma[256] then beta[256]
{
    __shared__ __align__(16) char hbuf[2][BPB * HSTR];   // 2 x 640 B

    const int tid  = threadIdx.x;
    const int w    = tid >> 6;        // wave 0..3
    const int l    = tid & 63;        // lane
    const int lrow = l & 15;          // A-row / C-col index
    const int kgrp = l >> 4;          // 0..3

    // ---- B fragments: Bf[kf][q]; kf 0,1 = U k 0-31/32-63; kf 2,3 = W ----
    half8 Bf[4][4];
#pragma unroll
    for (int kf = 0; kf < 4; ++kf) {
        const float* M = (kf < 2) ? U : W;
        const int krow0 = (kf & 1) * 32 + kgrp * 8;
#pragma unroll
        for (int q = 0; q < 4; ++q) {
            const int col = q * 64 + w * 16 + lrow;
#pragma unroll
            for (int j = 0; j < 8; ++j)
                Bf[kf][q][j] = (f16)M[(krow0 + j) * G4 + col];
        }
    }
    float bq[4];
#pragma unroll
    for (int q = 0; q < 4; ++q) bq[q] = bias[q * 64 + w * 16 + lrow];

    // ---- init h buffers (both parities) to zero; c scalar per lane ----
    if (tid < (2 * BPB * HSTR) / 16) ((uint4*)hbuf)[tid] = uint4{0, 0, 0, 0};
    float c = 0.0f;

    // ---- x addressing: A-row lrow -> batch lrow/4 (rows !=0 mod 4 = pad,
    //      they duplicate their group's batch; harmless) ----
    const int b_lane = lrow >> 2;
    const f16* xlane = x16 + ((size_t)(blockIdx.x * BPB + b_lane) * Tn) * Dn
                           + kgrp * 8;

    // h A-frag read addresses: batch b_lane, k-slice kgrp*8 (+32)
    const int rdA = b_lane * HSTR + kgrp * 16;
    const int rdB = rdA + 64;
    // h write: this lane's pair = (batch l>>4, unit 16w + lrow)
    const int wrb = (l >> 4) * HSTR + (w * 16 + lrow) * 2;

    const float wgj = wg[l], wbj = wb[l];
    const float bg0 = bgam[0], bb0 = bbet[0];

    __syncthreads();   // hbuf cleared

#define XLD0(T) (*(const half8*)(xlane + (size_t)(T) * Dn))
#define XLD1(T) (*(const half8*)(xlane + (size_t)(T) * Dn + 32))

    half8 A0 = XLD0(0), B0 = XLD1(0);
    half8 A1 = XLD0(1), B1 = XLD1(1);
    half8 A2 = XLD0(2), B2 = XLD1(2);
    half8 A3 = XLD0(3), B3 = XLD1(3);

#define STEP(AX0, AX1, P, TNEXT) do {                                        \
        /* x-side: independent of h, issued before the barrier */            \
        f32x4 z0 = {bq[0], bq[0], bq[0], bq[0]};                             \
        f32x4 z1 = {bq[1], bq[1], bq[1], bq[1]};                             \
        f32x4 z2 = {bq[2], bq[2], bq[2], bq[2]};                             \
        f32x4 z3 = {bq[3], bq[3], bq[3], bq[3]};                             \
        z0 = __builtin_amdgcn_mfma_f32_16x16x32_f16(AX0, Bf[2][0], z0,0,0,0);\
        z1 = __builtin_amdgcn_mfma_f32_16x16x32_f16(AX0, Bf[2][1], z1,0,0,0);\
        z2 = __builtin_amdgcn_mfma_f32_16x16x32_f16(AX0, Bf[2][2], z2,0,0,0);\
        z3 = __builtin_amdgcn_mfma_f32_16x16x32_f16(AX0, Bf[2][3], z3,0,0,0);\
        z0 = __builtin_amdgcn_mfma_f32_16x16x32_f16(AX1, Bf[3][0], z0,0,0,0);\
        z1 = __builtin_amdgcn_mfma_f32_16x16x32_f16(AX1, Bf[3][1], z1,0,0,0);\
        z2 = __builtin_amdgcn_mfma_f32_16x16x32_f16(AX1, Bf[3][2], z2,0,0,0);\
        z3 = __builtin_amdgcn_mfma_f32_16x16x32_f16(AX1, Bf[3][3], z3,0,0,0);\
        AX0 = XLD0(TNEXT); AX1 = XLD1(TNEXT);   /* stays in flight */        \
        /* h(t) visibility: drain LDS writes, raw barrier (no vmcnt drain) */\
        asm volatile("s_waitcnt lgkmcnt(0)" ::: "memory");                   \
        __builtin_amdgcn_s_barrier();                                        \
        asm volatile("" ::: "memory");                                       \
        const char* hb = hbuf[P];                                            \
        half8 ah0 = *(const half8*)(hb + rdA);                               \
        half8 ah1 = *(const half8*)(hb + rdB);                               \
        z0 = __builtin_amdgcn_mfma_f32_16x16x32_f16(ah0, Bf[0][0], z0,0,0,0);\
        z1 = __builtin_amdgcn_mfma_f32_16x16x32_f16(ah0, Bf[0][1], z1,0,0,0);\
        z2 = __builtin_amdgcn_mfma_f32_16x16x32_f16(ah0, Bf[0][2], z2,0,0,0);\
        z3 = __builtin_amdgcn_mfma_f32_16x16x32_f16(ah0, Bf[0][3], z3,0,0,0);\
        z0 = __builtin_amdgcn_mfma_f32_16x16x32_f16(ah1, Bf[1][0], z0,0,0,0);\
        z1 = __builtin_amdgcn_mfma_f32_16x16x32_f16(ah1, Bf[1][1], z1,0,0,0);\
        z2 = __builtin_amdgcn_mfma_f32_16x16x32_f16(ah1, Bf[1][2], z2,0,0,0);\
        z3 = __builtin_amdgcn_mfma_f32_16x16x32_f16(ah1, Bf[1][3], z3,0,0,0);\
        /* lane-local update: ONE pair (reg 0 = C-row 4*(l>>4)) */           \
        {                                                                    \
            float gi = sigmoidf_fast(z0[0]);                                 \
            float gf = sigmoidf_fast(z1[0]);                                 \
            float gg = sigmoidf_fast(z2[0]);                                 \
            float go = sigmoidf_fast(z3[0]);                                 \
            c = fmaf(gf, c, gi * gg);                                        \
            float hh = go * sigmoidf_fast(c);                                \
            *(f16*)(hbuf[(P) ^ 1] + wrb) = (f16)hh;                          \
        }                                                                    \
    } while (0)

    for (int t = 0; t < Tn; t += 4) {
        const int tA = t + 4 < Tn ? t + 4 : Tn - 1;
        const int tB = t + 5 < Tn ? t + 5 : Tn - 1;
        const int tC = t + 6 < Tn ? t + 6 : Tn - 1;
        const int tD = t + 7 < Tn ? t + 7 : Tn - 1;
        STEP(A0, B0, 0, tA);   // step t   reads hbuf[0], writes hbuf[1]
        STEP(A1, B1, 1, tB);
        STEP(A2, B2, 0, tC);
        STEP(A3, B3, 1, tD);
    }
#undef STEP
#undef XLD0
#undef XLD1

    __syncthreads();   // final h(T) writes (in hbuf[0]) visible

    // ---- heads: wave w reduces batch w; lane j holds unit j ----
    {
        const float hv = (float)*(const f16*)(hbuf[0] + w * HSTR + l * 2);
        float vg = hv * wgj, vb = hv * wbj;
#pragma unroll
        for (int off = 32; off > 0; off >>= 1) {
            vg += __shfl_xor(vg, off, 64);
            vb += __shfl_xor(vb, off, 64);
        }
        if (l == 0) {
            out[blockIdx.x * BPB + w]       = vg + bg0;
            out[Bsz + blockIdx.x * BPB + w] = vb + bb0;
        }
    }
}

// ---------------- fallback (R4 fused, no workspace) ----------------
typedef f16 f16x2 __attribute__((ext_vector_type(2)));
typedef f16 f16x4 __attribute__((ext_vector_type(4)));

__device__ __forceinline__ float dot2acc(f16x2 a, f16x2 b, float acc) {
    return acc + (float)a[0] * (float)b[0] + (float)a[1] * (float)b[1];
}
__device__ __forceinline__ f16x2 asf16x2(unsigned int u) {
    union { unsigned int u; f16x2 h; } v; v.u = u; return v.h;
}

constexpr int CHS = 32;
constexpr int NC  = Tn / CHS;
constexpr int XSTR = 72;

__global__ __launch_bounds__(128, 1) void lstm_film_fused(
    const float* __restrict__ x, const float* __restrict__ W,
    const float* __restrict__ U, const float* __restrict__ bias,
    const float* __restrict__ wg, const float* __restrict__ bgam,
    const float* __restrict__ wb, const float* __restrict__ bbet,
    float* __restrict__ out)
{
    __shared__ f16x4 zbuf[2][CHS][Hn];
    __shared__ __align__(16) f16 hl[Hn];
    __shared__ __align__(16) f16 xstage[CHS * XSTR];
    const int wave = threadIdx.x >> 6, j = threadIdx.x & 63, b = blockIdx.x;
    const float* xb = x + (size_t)b * Tn * Dn;
    if (wave == 1) {
        f16x2 Wp[4][32]; float bg[4];
#pragma unroll
        for (int q = 0; q < 4; ++q) {
#pragma unroll
            for (int k2 = 0; k2 < 32; ++k2) {
                Wp[q][k2][0] = (f16)W[(2 * k2 + 0) * G4 + q * 64 + j];
                Wp[q][k2][1] = (f16)W[(2 * k2 + 1) * G4 + q * 64 + j];
            }
            bg[q] = bias[q * 64 + j];
        }
        const int row0 = j >> 4, part = j & 15;
        float4 xld[8];
#pragma unroll
        for (int p = 0; p < 8; ++p)
            xld[p] = ((const float4*)(xb + (size_t)(p * 4 + row0) * Dn))[part];
        for (int ch = 0; ch < NC; ++ch) {
#pragma unroll
            for (int p = 0; p < 8; ++p) {
                float4 v = xld[p];
                f16x4 o; o[0]=(f16)v.x; o[1]=(f16)v.y; o[2]=(f16)v.z; o[3]=(f16)v.w;
                *(f16x4*)(xstage + (p * 4 + row0) * XSTR + part * 4) = o;
            }
            if (ch + 1 < NC) {
#pragma unroll
                for (int p = 0; p < 8; ++p)
                    xld[p] = ((const float4*)(xb +
                        (size_t)((ch + 1) * CHS + p * 4 + row0) * Dn))[part];
            }
#pragma unroll 1
            for (int s = 0; s < CHS; ++s) {
                const uint4* xr = (const uint4*)(xstage + s * XSTR);
                float a0 = bg[0], a1 = bg[1], a2 = bg[2], a3 = bg[3];
#pragma unroll
                for (int kk = 0; kk < 8; ++kk) {
                    uint4 w4 = xr[kk];
                    f16x2 p0 = asf16x2(w4.x), p1 = asf16x2(w4.y);
                    f16x2 p2 = asf16x2(w4.z), p3 = asf16x2(w4.w);
                    a0=dot2acc(p0,Wp[0][kk*4+0],a0); a1=dot2acc(p0,Wp[1][kk*4+0],a1);
                    a2=dot2acc(p0,Wp[2][kk*4+0],a2); a3=dot2acc(p0,Wp[3][kk*4+0],a3);
                    a0=dot2acc(p1,Wp[0][kk*4+1],a0); a1=dot2acc(p1,Wp[1][kk*4+1],a1);
                    a2=dot2acc(p1,Wp[2][kk*4+1],a2); a3=dot2acc(p1,Wp[3][kk*4+1],a3);
                    a0=dot2acc(p2,Wp[0][kk*4+2],a0); a1=dot2acc(p2,Wp[1][kk*4+2],a1);
                    a2=dot2acc(p2,Wp[2][kk*4+2],a2); a3=dot2acc(p2,Wp[3][kk*4+2],a3);
                    a0=dot2acc(p3,Wp[0][kk*4+3],a0); a1=dot2acc(p3,Wp[1][kk*4+3],a1);
                    a2=dot2acc(p3,Wp[2][kk*4+3],a2); a3=dot2acc(p3,Wp[3][kk*4+3],a3);
                }
                f16x4 zo; zo[0]=(f16)a0; zo[1]=(f16)a1; zo[2]=(f16)a2; zo[3]=(f16)a3;
                zbuf[ch & 1][s][j] = zo;
            }
            __syncthreads();
        }
    } else {
        f16x2 Up[4][32];
#pragma unroll
        for (int q = 0; q < 4; ++q)
#pragma unroll
            for (int k2 = 0; k2 < 32; ++k2) {
                Up[q][k2][0] = (f16)U[(2 * k2 + 0) * G4 + q * 64 + j];
                Up[q][k2][1] = (f16)U[(2 * k2 + 1) * G4 + q * 64 + j];
            }
        const float wgj = wg[j], wbj = wb[j];
        const float bg0 = bgam[0], bb0 = bbet[0];
        float h = 0.0f, cc = 0.0f;
        hl[j] = (f16)0.0f;
        auto consume = [&](int chk) {
            const int bb2 = chk & 1;
            f16x4 zc = zbuf[bb2][0][j];
#pragma unroll 1
            for (int s = 0; s < CHS; ++s) {
                f16x4 zn = zbuf[bb2][(s + 1 < CHS) ? s + 1 : CHS - 1][j];
                float a0 = (float)zc[0], a1 = (float)zc[1];
                float a2 = (float)zc[2], a3 = (float)zc[3];
                const uint4* hv = (const uint4*)hl;
#pragma unroll
                for (int kk = 0; kk < 8; ++kk) {
                    uint4 w4 = hv[kk];
                    f16x2 p0 = asf16x2(w4.x), p1 = asf16x2(w4.y);
                    f16x2 p2 = asf16x2(w4.z), p3 = asf16x2(w4.w);
                    a0=dot2acc(p0,Up[0][kk*4+0],a0); a1=dot2acc(p0,Up[1][kk*4+0],a1);
                    a2=dot2acc(p0,Up[2][kk*4+0],a2); a3=dot2acc(p0,Up[3][kk*4+0],a3);
                    a0=dot2acc(p1,Up[0][kk*4+1],a0); a1=dot2acc(p1,Up[1][kk*4+1],a1);
                    a2=dot2acc(p1,Up[2][kk*4+1],a2); a3=dot2acc(p1,Up[3][kk*4+1],a3);
                    a0=dot2acc(p2,Up[0][kk*4+2],a0); a1=dot2acc(p2,Up[1][kk*4+2],a1);
                    a2=dot2acc(p2,Up[2][kk*4+2],a2); a3=dot2acc(p2,Up[3][kk*4+2],a3);
                    a0=dot2acc(p3,Up[0][kk*4+3],a0); a1=dot2acc(p3,Up[1][kk*4+3],a1);
                    a2=dot2acc(p3,Up[2][kk*4+3],a2); a3=dot2acc(p3,Up[3][kk*4+3],a3);
                }
                float gi = sigmoidf_fast(a0), gf = sigmoidf_fast(a1);
                float gg = sigmoidf_fast(a2), go = sigmoidf_fast(a3);
                cc = fmaf(gf, cc, gi * gg);
                h = go * sigmoidf_fast(cc);
                hl[j] = (f16)h;
                zc = zn;
            }
        };
        __syncthreads();
        for (int ch = 1; ch < NC; ++ch) { consume(ch - 1); __syncthreads(); }
        consume(NC - 1);
        float vg = h * wgj, vb = h * wbj;
#pragma unroll
        for (int off = 32; off > 0; off >>= 1) {
            vg += __shfl_xor(vg, off, 64);
            vb += __shfl_xor(vb, off, 64);
        }
        if (j == 0) { out[b] = vg + bg0; out[Bsz + b] = vb + bb0; }
    }
}

extern "C" void kernel_launch(void* const* d_in, const int* in_sizes, int n_in,
                              void* d_out, int out_size, void* d_ws, size_t ws_size,
                              hipStream_t stream) {
    const float* x    = (const float*)d_in[0];
    const float* W    = (const float*)d_in[2];
    const float* U    = (const float*)d_in[3];
    const float* bias = (const float*)d_in[4];
    const float* wg   = (const float*)d_in[5];
    const float* bgam = (const float*)d_in[6];
    const float* wb   = (const float*)d_in[7];
    const float* bbet = (const float*)d_in[8];
    float* out = (float*)d_out;

    const size_t x16_bytes = (size_t)Bsz * Tn * Dn * sizeof(f16);  // 64 MB
    if (ws_size >= x16_bytes) {
        f16* x16 = (f16*)d_ws;
        const int n8 = Bsz * Tn * Dn / 8;
        xcvt_kernel<<<2048, 256, 0, stream>>>(x, x16, n8);
        lstm_film_mfma<<<Bsz / BPB, 256, 0, stream>>>(x16, W, U, bias,
                                                      wg, bgam, wb, bbet, out);
    } else {
        lstm_film_fused<<<Bsz, 128, 0, stream>>>(x, W, U, bias,
                                                 wg, bgam, wb, bbet, out);
    }
}

// Round 9
// 504.320 us; speedup vs baseline: 2.2130x; 1.0371x over previous
//
#include <hip/hip_runtime.h>

// FiLM LSTM, R9: MFMA recurrence, 4-step-packed x-projection.
//   64 blocks x 256 threads (4 waves), BPB=4 batches/block, no workspace.
//   Every 4 steps: XZ[16x256] = Xpack[16x64] @ W[64x256] + bias, where
//     M-row 4b+s = x(batch b, t0+s)  ->  lane's C-reg r holds zx for its own
//     (batch, unit) at step t0+r. Full M-density, 8 MFMAs per 4 steps.
//   Every step: HZ[16x256] = Hpad[16x64] @ U[64x256] (batches at rows 0,4,8,12,
//     reg0 real), 8 independent MFMAs; z = hza[0]+hzb[0]+xz[s]; lane-local
//     update (1 (batch,unit) pair/lane); h via double-buffered LDS (HSTR=160B,
//     conflict-free); sync = lgkmcnt(0) + raw s_barrier (x loads in flight).

typedef _Float16 f16;
typedef f16  half8 __attribute__((ext_vector_type(8)));
typedef float f32x4 __attribute__((ext_vector_type(4)));

constexpr int Bsz = 256;
constexpr int Tn  = 2048;
constexpr int Dn  = 64;
constexpr int G4  = 256;          // 4*H
constexpr int BPB = 4;            // batches per block
constexpr int HSTR = 160;         // bytes per batch row in h LDS

__device__ __forceinline__ float sigmoidf_fast(float z) {
    return __builtin_amdgcn_rcpf(1.0f + __expf(-z));
}

__global__ __launch_bounds__(256, 1) void lstm_film_mfma(
    const float* __restrict__ x,     // [B,T,64] f32
    const float* __restrict__ W,     // [64,256]
    const float* __restrict__ U,     // [64,256]
    const float* __restrict__ bias,  // [256]
    const float* __restrict__ wg, const float* __restrict__ bgam,
    const float* __restrict__ wb, const float* __restrict__ bbet,
    float* __restrict__ out)         // gamma[256] then beta[256]
{
    __shared__ __align__(16) char hbuf[2][BPB * HSTR];   // 2 x 640 B

    const int tid  = threadIdx.x;
    const int w    = tid >> 6;        // wave 0..3
    const int l    = tid & 63;        // lane
    const int lrow = l & 15;          // A-row / C-col index
    const int kgrp = l >> 4;          // 0..3

    // ---- B fragments: Bf[kf][q]; kf 0,1 = U k 0-31/32-63; kf 2,3 = W ----
    half8 Bf[4][4];
#pragma unroll
    for (int kf = 0; kf < 4; ++kf) {
        const float* M = (kf < 2) ? U : W;
        const int krow0 = (kf & 1) * 32 + kgrp * 8;
#pragma unroll
        for (int q = 0; q < 4; ++q) {
            const int col = q * 64 + w * 16 + lrow;
#pragma unroll
            for (int j = 0; j < 8; ++j)
                Bf[kf][q][j] = (f16)M[(krow0 + j) * G4 + col];
        }
    }
    float bq[4];
#pragma unroll
    for (int q = 0; q < 4; ++q) bq[q] = bias[q * 64 + w * 16 + lrow];

    // ---- init h buffers (both parities) to zero; c scalar per lane ----
    if (tid < (2 * BPB * HSTR) / 16) ((uint4*)hbuf)[tid] = uint4{0, 0, 0, 0};
    float c = 0.0f;

    // ---- x addressing: A-row lrow = 4b+s -> batch lrow>>2, step off lrow&3
    const float* xlane = x + ((size_t)(blockIdx.x * BPB + (lrow >> 2)) * Tn
                              + (lrow & 3)) * Dn + kgrp * 8;

    // h A-frag reads: batch lrow>>2 (rows 4b+* duplicate batch b; pad rows
    // feed pad C rows), k-slice kgrp*8 (+32)
    const int rdA = (lrow >> 2) * HSTR + kgrp * 16;
    const int rdB = rdA + 64;
    // h write: this lane's pair = (batch l>>4, unit 16w + lrow)
    const int wrb = (l >> 4) * HSTR + (w * 16 + lrow) * 2;

    const float wgj = wg[l], wbj = wb[l];
    const float bg0 = bgam[0], bb0 = bbet[0];

    __syncthreads();   // hbuf cleared

#define XL(R, TB) do {                                                       \
        const float* p_ = xlane + (size_t)(TB) * (4 * Dn);                   \
        R[0] = *(const float4*)(p_);      R[1] = *(const float4*)(p_ + 4);   \
        R[2] = *(const float4*)(p_ + 32); R[3] = *(const float4*)(p_ + 36);  \
    } while (0)

    float4 RA[4], RB[4];
    XL(RA, 0); XL(RB, 1);

    f32x4 xzA0, xzA1, xzA2, xzA3, xzB0, xzB1, xzB2, xzB3;

    // 4-step x block: cvt raw f32 -> A-frags, 8 MFMAs, reissue loads
#define XBLOCK(XZ, R, TBN) do {                                              \
        half8 af0, af1;                                                      \
        af0[0]=(f16)R[0].x; af0[1]=(f16)R[0].y; af0[2]=(f16)R[0].z;          \
        af0[3]=(f16)R[0].w; af0[4]=(f16)R[1].x; af0[5]=(f16)R[1].y;          \
        af0[6]=(f16)R[1].z; af0[7]=(f16)R[1].w;                              \
        af1[0]=(f16)R[2].x; af1[1]=(f16)R[2].y; af1[2]=(f16)R[2].z;          \
        af1[3]=(f16)R[2].w; af1[4]=(f16)R[3].x; af1[5]=(f16)R[3].y;          \
        af1[6]=(f16)R[3].z; af1[7]=(f16)R[3].w;                              \
        XL(R, TBN);                       /* refill, stays in flight */      \
        XZ##0 = f32x4{bq[0], bq[0], bq[0], bq[0]};                           \
        XZ##1 = f32x4{bq[1], bq[1], bq[1], bq[1]};                           \
        XZ##2 = f32x4{bq[2], bq[2], bq[2], bq[2]};                           \
        XZ##3 = f32x4{bq[3], bq[3], bq[3], bq[3]};                           \
        XZ##0 = __builtin_amdgcn_mfma_f32_16x16x32_f16(af0, Bf[2][0], XZ##0,0,0,0);\
        XZ##1 = __builtin_amdgcn_mfma_f32_16x16x32_f16(af0, Bf[2][1], XZ##1,0,0,0);\
        XZ##2 = __builtin_amdgcn_mfma_f32_16x16x32_f16(af0, Bf[2][2], XZ##2,0,0,0);\
        XZ##3 = __builtin_amdgcn_mfma_f32_16x16x32_f16(af0, Bf[2][3], XZ##3,0,0,0);\
        XZ##0 = __builtin_amdgcn_mfma_f32_16x16x32_f16(af1, Bf[3][0], XZ##0,0,0,0);\
        XZ##1 = __builtin_amdgcn_mfma_f32_16x16x32_f16(af1, Bf[3][1], XZ##1,0,0,0);\
        XZ##2 = __builtin_amdgcn_mfma_f32_16x16x32_f16(af1, Bf[3][2], XZ##2,0,0,0);\
        XZ##3 = __builtin_amdgcn_mfma_f32_16x16x32_f16(af1, Bf[3][3], XZ##3,0,0,0);\
    } while (0)

    // one recurrence step; S is a literal 0..3, P = parity (reads hbuf[P])
#define HSTEP(XZ, S, P) do {                                                 \
        asm volatile("s_waitcnt lgkmcnt(0)" ::: "memory");                   \
        __builtin_amdgcn_s_barrier();                                        \
        asm volatile("" ::: "memory");                                       \
        const char* hb = hbuf[P];                                            \
        half8 ah0 = *(const half8*)(hb + rdA);                               \
        half8 ah1 = *(const half8*)(hb + rdB);                               \
        const f32x4 zr = {0.f, 0.f, 0.f, 0.f};                               \
        f32x4 ha0 = __builtin_amdgcn_mfma_f32_16x16x32_f16(ah0, Bf[0][0], zr,0,0,0);\
        f32x4 ha1 = __builtin_amdgcn_mfma_f32_16x16x32_f16(ah0, Bf[0][1], zr,0,0,0);\
        f32x4 ha2 = __builtin_amdgcn_mfma_f32_16x16x32_f16(ah0, Bf[0][2], zr,0,0,0);\
        f32x4 ha3 = __builtin_amdgcn_mfma_f32_16x16x32_f16(ah0, Bf[0][3], zr,0,0,0);\
        f32x4 hb0 = __builtin_amdgcn_mfma_f32_16x16x32_f16(ah1, Bf[1][0], zr,0,0,0);\
        f32x4 hb1 = __builtin_amdgcn_mfma_f32_16x16x32_f16(ah1, Bf[1][1], zr,0,0,0);\
        f32x4 hb2 = __builtin_amdgcn_mfma_f32_16x16x32_f16(ah1, Bf[1][2], zr,0,0,0);\
        f32x4 hb3 = __builtin_amdgcn_mfma_f32_16x16x32_f16(ah1, Bf[1][3], zr,0,0,0);\
        const float zi = ha0[0] + hb0[0] + XZ##0[S];                         \
        const float zf = ha1[0] + hb1[0] + XZ##1[S];                         \
        const float zg = ha2[0] + hb2[0] + XZ##2[S];                         \
        const float zo = ha3[0] + hb3[0] + XZ##3[S];                         \
        const float gi = sigmoidf_fast(zi);                                  \
        const float gf = sigmoidf_fast(zf);                                  \
        const float gg = sigmoidf_fast(zg);                                  \
        const float go = sigmoidf_fast(zo);                                  \
        c = fmaf(gf, c, gi * gg);                                            \
        const float hh = go * sigmoidf_fast(c);                              \
        *(f16*)(hbuf[(P) ^ 1] + wrb) = (f16)hh;                              \
    } while (0)

    constexpr int NTB = Tn / 4;   // 512 four-step blocks
    for (int tb = 0; tb < NTB; tb += 2) {
        const int tbn0 = tb + 2 < NTB ? tb + 2 : NTB - 1;
        const int tbn1 = tb + 3 < NTB ? tb + 3 : NTB - 1;
        XBLOCK(xzA, RA, tbn0);
        HSTEP(xzA, 0, 0); HSTEP(xzA, 1, 1); HSTEP(xzA, 2, 0); HSTEP(xzA, 3, 1);
        XBLOCK(xzB, RB, tbn1);
        HSTEP(xzB, 0, 0); HSTEP(xzB, 1, 1); HSTEP(xzB, 2, 0); HSTEP(xzB, 3, 1);
    }
#undef HSTEP
#undef XBLOCK
#undef XL

    __syncthreads();   // final h(T) writes (in hbuf[0]) visible

    // ---- heads: wave w reduces batch w; lane l holds unit l ----
    {
        const float hv = (float)*(const f16*)(hbuf[0] + w * HSTR + l * 2);
        float vg = hv * wgj, vb = hv * wbj;
#pragma unroll
        for (int off = 32; off > 0; off >>= 1) {
            vg += __shfl_xor(vg, off, 64);
            vb += __shfl_xor(vb, off, 64);
        }
        if (l == 0) {
            out[blockIdx.x * BPB + w]       = vg + bg0;
            out[Bsz + blockIdx.x * BPB + w] = vb + bb0;
        }
    }
}

extern "C" void kernel_launch(void* const* d_in, const int* in_sizes, int n_in,
                              void* d_out, int out_size, void* d_ws, size_t ws_size,
                              hipStream_t stream) {
    const float* x    = (const float*)d_in[0];
    const float* W    = (const float*)d_in[2];
    const float* U    = (const float*)d_in[3];
    const float* bias = (const float*)d_in[4];
    const float* wg   = (const float*)d_in[5];
    const float* bgam = (const float*)d_in[6];
    const float* wb   = (const float*)d_in[7];
    const float* bbet = (const float*)d_in[8];
    float* out = (float*)d_out;

    lstm_film_mfma<<<Bsz / BPB, 256, 0, stream>>>(x, W, U, bias,
                                                  wg, bgam, wb, bbet, out);
}

// Round 10
// 461.066 us; speedup vs baseline: 2.4206x; 1.0938x over previous
//
#include <hip/hip_runtime.h>

// FiLM LSTM, R10: MFMA recurrence, chain-shortened.
//   64 blocks x 256 threads (4 waves), BPB=4 batches/block, no workspace.
//   W,U,bias pre-scaled by -log2(e) at fragment load: MFMA emits z' = -1.4427 z,
//   sigma(z) = rcp(1+exp2(z')). Shared-rcp pairs: sig(i)sig(g) and h=sig(o)sig(c)
//   each cost ONE rcp. 8 trans-ops/step (was 10).
//   xz (x@W) computed one 4-step block ahead; its 8 MFMAs issue in the
//   ds_read-latency shadow right after the barrier. h-MFMA chains C-in=xz
//   (no VALU z-adds). h exchange via double-buffered LDS, HSTR=160B;
//   per-step sync = lgkmcnt(0) + raw s_barrier (x loads stay in flight).

typedef _Float16 f16;
typedef f16  half8 __attribute__((ext_vector_type(8)));
typedef float f32x4 __attribute__((ext_vector_type(4)));

constexpr int Bsz = 256;
constexpr int Tn  = 2048;
constexpr int Dn  = 64;
constexpr int G4  = 256;          // 4*H
constexpr int BPB = 4;            // batches per block
constexpr int HSTR = 160;         // bytes per batch row in h LDS

__global__ __launch_bounds__(256, 1) void lstm_film_mfma(
    const float* __restrict__ x,     // [B,T,64] f32
    const float* __restrict__ W,     // [64,256]
    const float* __restrict__ U,     // [64,256]
    const float* __restrict__ bias,  // [256]
    const float* __restrict__ wg, const float* __restrict__ bgam,
    const float* __restrict__ wb, const float* __restrict__ bbet,
    float* __restrict__ out)         // gamma[256] then beta[256]
{
    __shared__ __align__(16) char hbuf[2][BPB * HSTR];   // 2 x 640 B

    const int tid  = threadIdx.x;
    const int w    = tid >> 6;        // wave 0..3
    const int l    = tid & 63;        // lane
    const int lrow = l & 15;          // A-row / C-col index
    const int kgrp = l >> 4;          // 0..3

    const float NK = -1.44269504f;    // -log2(e), folded into weights

    // ---- B fragments (pre-scaled): kf 0,1 = U k 0-31/32-63; kf 2,3 = W ----
    half8 Bf[4][4];
#pragma unroll
    for (int kf = 0; kf < 4; ++kf) {
        const float* M = (kf < 2) ? U : W;
        const int krow0 = (kf & 1) * 32 + kgrp * 8;
#pragma unroll
        for (int q = 0; q < 4; ++q) {
            const int col = q * 64 + w * 16 + lrow;
#pragma unroll
            for (int j = 0; j < 8; ++j)
                Bf[kf][q][j] = (f16)(M[(krow0 + j) * G4 + col] * NK);
        }
    }
    float bq[4];
#pragma unroll
    for (int q = 0; q < 4; ++q) bq[q] = bias[q * 64 + w * 16 + lrow] * NK;

    // ---- init h buffers (both parities) to zero; c scalar per lane ----
    if (tid < (2 * BPB * HSTR) / 16) ((uint4*)hbuf)[tid] = uint4{0, 0, 0, 0};
    float c = 0.0f;

    // ---- x addressing: A-row lrow = 4b+s -> batch lrow>>2, step off lrow&3
    const float* xlane = x + ((size_t)(blockIdx.x * BPB + (lrow >> 2)) * Tn
                              + (lrow & 3)) * Dn + kgrp * 8;

    const int rdA = (lrow >> 2) * HSTR + kgrp * 16;
    const int rdB = rdA + 64;
    const int wrb = (l >> 4) * HSTR + (w * 16 + lrow) * 2;

    const float wgj = wg[l], wbj = wb[l];
    const float bg0 = bgam[0], bb0 = bbet[0];

    __syncthreads();   // hbuf cleared

#define XL(R, TB) do {                                                       \
        const float* p_ = xlane + (size_t)(TB) * (4 * Dn);                   \
        R[0] = *(const float4*)(p_);      R[1] = *(const float4*)(p_ + 4);   \
        R[2] = *(const float4*)(p_ + 32); R[3] = *(const float4*)(p_ + 36);  \
    } while (0)

    float4 RA[4], RB[4];
    XL(RA, 0); XL(RB, 1);

    f32x4 xzA0, xzA1, xzA2, xzA3, xzB0, xzB1, xzB2, xzB3;

    // 4-step x block: cvt f32 -> A-frags, 8 MFMAs (pre-scaled W), refill R
#define XBLOCK(XZ, R, TBN) do {                                              \
        half8 af0, af1;                                                      \
        af0[0]=(f16)R[0].x; af0[1]=(f16)R[0].y; af0[2]=(f16)R[0].z;          \
        af0[3]=(f16)R[0].w; af0[4]=(f16)R[1].x; af0[5]=(f16)R[1].y;          \
        af0[6]=(f16)R[1].z; af0[7]=(f16)R[1].w;                              \
        af1[0]=(f16)R[2].x; af1[1]=(f16)R[2].y; af1[2]=(f16)R[2].z;          \
        af1[3]=(f16)R[2].w; af1[4]=(f16)R[3].x; af1[5]=(f16)R[3].y;          \
        af1[6]=(f16)R[3].z; af1[7]=(f16)R[3].w;                              \
        XL(R, TBN);                       /* refill, stays in flight */      \
        XZ##0 = f32x4{bq[0], bq[0], bq[0], bq[0]};                           \
        XZ##1 = f32x4{bq[1], bq[1], bq[1], bq[1]};                           \
        XZ##2 = f32x4{bq[2], bq[2], bq[2], bq[2]};                           \
        XZ##3 = f32x4{bq[3], bq[3], bq[3], bq[3]};                           \
        XZ##0 = __builtin_amdgcn_mfma_f32_16x16x32_f16(af0, Bf[2][0], XZ##0,0,0,0);\
        XZ##1 = __builtin_amdgcn_mfma_f32_16x16x32_f16(af0, Bf[2][1], XZ##1,0,0,0);\
        XZ##2 = __builtin_amdgcn_mfma_f32_16x16x32_f16(af0, Bf[2][2], XZ##2,0,0,0);\
        XZ##3 = __builtin_amdgcn_mfma_f32_16x16x32_f16(af0, Bf[2][3], XZ##3,0,0,0);\
        XZ##0 = __builtin_amdgcn_mfma_f32_16x16x32_f16(af1, Bf[3][0], XZ##0,0,0,0);\
        XZ##1 = __builtin_amdgcn_mfma_f32_16x16x32_f16(af1, Bf[3][1], XZ##1,0,0,0);\
        XZ##2 = __builtin_amdgcn_mfma_f32_16x16x32_f16(af1, Bf[3][2], XZ##2,0,0,0);\
        XZ##3 = __builtin_amdgcn_mfma_f32_16x16x32_f16(af1, Bf[3][3], XZ##3,0,0,0);\
    } while (0)

    // step pre: barrier + issue h ds_reads (ah0_/ah1_ in scope after)
#define HSTEP_PRE(P)                                                         \
        asm volatile("s_waitcnt lgkmcnt(0)" ::: "memory");                   \
        __builtin_amdgcn_s_barrier();                                        \
        asm volatile("" ::: "memory");                                       \
        const char* hb_ = hbuf[P];                                           \
        half8 ah0_ = *(const half8*)(hb_ + rdA);                             \
        half8 ah1_ = *(const half8*)(hb_ + rdB);

    // step post: chained h-MFMA (C-in = xz at reg0) + shared-rcp update
#define HSTEP_POST(XZ, S, P) do {                                            \
        f32x4 c0 = XZ##0; c0[0] = XZ##0[S];                                  \
        f32x4 c1 = XZ##1; c1[0] = XZ##1[S];                                  \
        f32x4 c2 = XZ##2; c2[0] = XZ##2[S];                                  \
        f32x4 c3 = XZ##3; c3[0] = XZ##3[S];                                  \
        c0 = __builtin_amdgcn_mfma_f32_16x16x32_f16(ah0_, Bf[0][0], c0,0,0,0);\
        c1 = __builtin_amdgcn_mfma_f32_16x16x32_f16(ah0_, Bf[0][1], c1,0,0,0);\
        c2 = __builtin_amdgcn_mfma_f32_16x16x32_f16(ah0_, Bf[0][2], c2,0,0,0);\
        c3 = __builtin_amdgcn_mfma_f32_16x16x32_f16(ah0_, Bf[0][3], c3,0,0,0);\
        c0 = __builtin_amdgcn_mfma_f32_16x16x32_f16(ah1_, Bf[1][0], c0,0,0,0);\
        c1 = __builtin_amdgcn_mfma_f32_16x16x32_f16(ah1_, Bf[1][1], c1,0,0,0);\
        c2 = __builtin_amdgcn_mfma_f32_16x16x32_f16(ah1_, Bf[1][2], c2,0,0,0);\
        c3 = __builtin_amdgcn_mfma_f32_16x16x32_f16(ah1_, Bf[1][3], c3,0,0,0);\
        /* z' = -1.4427*z at reg0; e = exp2(z') = exp(-z) */                 \
        const float ei = __builtin_amdgcn_exp2f(c0[0]);                      \
        const float ef = __builtin_amdgcn_exp2f(c1[0]);                      \
        const float eg = __builtin_amdgcn_exp2f(c2[0]);                      \
        const float eo = __builtin_amdgcn_exp2f(c3[0]);                      \
        const float sf  = __builtin_amdgcn_rcpf(1.0f + ef);                  \
        const float sig = __builtin_amdgcn_rcpf((1.0f + ei) * (1.0f + eg));  \
        c = fmaf(sf, c, sig);                                                \
        const float ec = __builtin_amdgcn_exp2f(c * NK);                     \
        const float hh = __builtin_amdgcn_rcpf((1.0f + eo) * (1.0f + ec));   \
        *(f16*)(hbuf[(P) ^ 1] + wrb) = (f16)hh;                              \
    } while (0)

    // prologue: xz for block 0; RA refilled with block 2
    XBLOCK(xzA, RA, 2);

    constexpr int NTB = Tn / 4;   // 512 four-step blocks
    for (int tb = 0; tb < NTB; tb += 2) {
        const int tbn0 = tb + 3 < NTB ? tb + 3 : NTB - 1;   // RB refill
        const int tbn1 = tb + 4 < NTB ? tb + 4 : NTB - 1;   // RA refill
        {   // block tb, step 0: XBLOCK(B) hides in ds_read shadow
            HSTEP_PRE(0)
            XBLOCK(xzB, RB, tbn0);
            HSTEP_POST(xzA, 0, 0);
        }
        { HSTEP_PRE(1) HSTEP_POST(xzA, 1, 1); }
        { HSTEP_PRE(0) HSTEP_POST(xzA, 2, 0); }
        { HSTEP_PRE(1) HSTEP_POST(xzA, 3, 1); }
        {   // block tb+1, step 0: XBLOCK(A) for block tb+2
            HSTEP_PRE(0)
            XBLOCK(xzA, RA, tbn1);
            HSTEP_POST(xzB, 0, 0);
        }
        { HSTEP_PRE(1) HSTEP_POST(xzB, 1, 1); }
        { HSTEP_PRE(0) HSTEP_POST(xzB, 2, 0); }
        { HSTEP_PRE(1) HSTEP_POST(xzB, 3, 1); }
    }
#undef HSTEP_PRE
#undef HSTEP_POST
#undef XBLOCK
#undef XL

    __syncthreads();   // final h(T) writes (in hbuf[0]) visible

    // ---- heads: wave w reduces batch w; lane l holds unit l ----
    {
        const float hv = (float)*(const f16*)(hbuf[0] + w * HSTR + l * 2);
        float vg = hv * wgj, vb = hv * wbj;
#pragma unroll
        for (int off = 32; off > 0; off >>= 1) {
            vg += __shfl_xor(vg, off, 64);
            vb += __shfl_xor(vb, off, 64);
        }
        if (l == 0) {
            out[blockIdx.x * BPB + w]       = vg + bg0;
            out[Bsz + blockIdx.x * BPB + w] = vb + bb0;
        }
    }
}

extern "C" void kernel_launch(void* const* d_in, const int* in_sizes, int n_in,
                              void* d_out, int out_size, void* d_ws, size_t ws_size,
                              hipStream_t stream) {
    const float* x    = (const float*)d_in[0];
    const float* W    = (const float*)d_in[2];
    const float* U    = (const float*)d_in[3];
    const float* bias = (const float*)d_in[4];
    const float* wg   = (const float*)d_in[5];
    const float* bgam = (const float*)d_in[6];
    const float* wb   = (const float*)d_in[7];
    const float* bbet = (const float*)d_in[8];
    float* out = (float*)d_out;

    lstm_film_mfma<<<Bsz / BPB, 256, 0, stream>>>(x, W, U, bias,
                                                  wg, bgam, wb, bbet, out);
}